// Round 7
// baseline (768.703 us; speedup 1.0000x reference)
//
#include <hip/hip_runtime.h>
#include <math.h>

#define N_TOK   16384
#define EDIM    64
#define NE      4096
#define NSLICE  16                       /* 16 slices x 256 codes */
#define TPB     256
#define ZQ_OFF  1
#define IDX_OFF (1 + N_TOK * EDIM)       /* 1048577 */
#define PERP_OFF (IDX_OFF + N_TOK)       /* 1064961 */

typedef unsigned long long u64;

// ---------------------------------------------------------------------------
// Kernel A: per-row squared norms replicating numpy pairwise_sum (n=64 path:
// 8 accumulators stride 8, then ((r0+r1)+(r2+r3))+((r4+r5)+(r6+r7))),
// with products ROUNDED before summation (contract off). Also zero-inits
// the histogram and loss accumulator in ws. (unchanged)
// ---------------------------------------------------------------------------
__global__ __launch_bounds__(256) void norms_zero_kernel(
    const float* __restrict__ z, const float* __restrict__ cb,
    float* __restrict__ nz, float* __restrict__ ne,
    int* __restrict__ hist, float* __restrict__ lossAcc) {
#pragma clang fp contract(off)
    int i = blockIdx.x * 256 + threadIdx.x;
    if (i < NE) hist[i] = 0;
    if (i == 0) lossAcc[0] = 0.0f;
    const float* row;
    float* dst;
    if (i < N_TOK)            { row = z  + (size_t)i * EDIM;           dst = nz + i; }
    else if (i < N_TOK + NE)  { row = cb + (size_t)(i - N_TOK) * EDIM; dst = ne + (i - N_TOK); }
    else return;

    float r[8];
#pragma unroll
    for (int j = 0; j < 8; ++j) { float v = row[j]; r[j] = v * v; }
#pragma unroll
    for (int b = 8; b < 64; b += 8) {
#pragma unroll
        for (int j = 0; j < 8; ++j) { float v = row[b + j]; r[j] = r[j] + v * v; }
    }
    dst[0] = ((r[0] + r[1]) + (r[2] + r[3])) + ((r[4] + r[5]) + (r[6] + r[7]));
}

// ---------------------------------------------------------------------------
// Kernel B (v8): ZERO-LDS. Codes streamed via wave-uniform
// global_load_dwordx4 (one 16B L2 request per load; 1MB codebook is
// L2/L3-resident). Six rounds showed the LDS trap: the single per-CU LDS
// pipe (~12cyc/wave-b128) needs big tiles to amortize, but big tiles kill
// occupancy (r6: 164 VGPR + 80KB LDS -> 1 block/CU, 11.4% occ, latency-
// bound 183us with both pipes at ~30%). Dropping LDS entirely removes the
// occupancy cap: ~150 VGPR -> 3-4 blocks/CU, 12-16 waves hide L2 latency.
// VMEM issue = 1 load per 4 FMA-instrs (8 VALU cyc) -> not a co-bottleneck.
// 1 token/thread (64 z-floats in regs), 4 codes/iter = 4 independent FMA
// chains (dep-latency-saturating), 64 loads in flight per iter.
// Numerics: per-(token,code) dot is the SAME sequential q-ascending,
// x->w-ascending fp32 FMA chain as every passing round (bits identical ->
// ties exact). d = fma(-2, dot, tnz+ne[k]); pack (d_bits<<32)|k, u64 min
// over ascending k == first-index tie-break (d>0 so float bits monotone).
// ---------------------------------------------------------------------------
__global__ __launch_bounds__(256, 1) void dist_argmin_kernel(
    const float* __restrict__ z, const float* __restrict__ cb,
    const float* __restrict__ nz, const float* __restrict__ ne,
    u64* __restrict__ part) {
    const int tid   = threadIdx.x;
    const int token = blockIdx.x * 256 + tid;
    const int slice = blockIdx.y;

    float zr[EDIM];
    {
        const float4* zp = (const float4*)(z + (size_t)token * EDIM);
#pragma unroll
        for (int j = 0; j < 16; ++j) {
            float4 v = zp[j];
            zr[4 * j + 0] = v.x; zr[4 * j + 1] = v.y;
            zr[4 * j + 2] = v.z; zr[4 * j + 3] = v.w;
        }
    }
    const float tnz = nz[token];
    u64 best = ~0ull;
    const int kb0 = slice * 256;

#pragma unroll 1
    for (int k = 0; k < 256; k += 4) {
        const float4* e0 = (const float4*)(cb + (size_t)(kb0 + k + 0) * EDIM);
        const float4* e1 = (const float4*)(cb + (size_t)(kb0 + k + 1) * EDIM);
        const float4* e2 = (const float4*)(cb + (size_t)(kb0 + k + 2) * EDIM);
        const float4* e3 = (const float4*)(cb + (size_t)(kb0 + k + 3) * EDIM);
        float d0 = 0.f, d1 = 0.f, d2 = 0.f, d3 = 0.f;
#pragma unroll
        for (int q = 0; q < 16; ++q) {
            float4 a = e0[q];
            float4 b = e1[q];
            float4 c = e2[q];
            float4 e = e3[q];
            d0 = __builtin_fmaf(zr[4 * q + 0], a.x, d0);
            d0 = __builtin_fmaf(zr[4 * q + 1], a.y, d0);
            d0 = __builtin_fmaf(zr[4 * q + 2], a.z, d0);
            d0 = __builtin_fmaf(zr[4 * q + 3], a.w, d0);
            d1 = __builtin_fmaf(zr[4 * q + 0], b.x, d1);
            d1 = __builtin_fmaf(zr[4 * q + 1], b.y, d1);
            d1 = __builtin_fmaf(zr[4 * q + 2], b.z, d1);
            d1 = __builtin_fmaf(zr[4 * q + 3], b.w, d1);
            d2 = __builtin_fmaf(zr[4 * q + 0], c.x, d2);
            d2 = __builtin_fmaf(zr[4 * q + 1], c.y, d2);
            d2 = __builtin_fmaf(zr[4 * q + 2], c.z, d2);
            d2 = __builtin_fmaf(zr[4 * q + 3], c.w, d2);
            d3 = __builtin_fmaf(zr[4 * q + 0], e.x, d3);
            d3 = __builtin_fmaf(zr[4 * q + 1], e.y, d3);
            d3 = __builtin_fmaf(zr[4 * q + 2], e.z, d3);
            d3 = __builtin_fmaf(zr[4 * q + 3], e.w, d3);
        }
        const float s0 = ne[kb0 + k + 0];
        const float s1 = ne[kb0 + k + 1];
        const float s2 = ne[kb0 + k + 2];
        const float s3 = ne[kb0 + k + 3];
        const float t0 = __builtin_fmaf(-2.0f, d0, tnz + s0);
        const float t1 = __builtin_fmaf(-2.0f, d1, tnz + s1);
        const float t2 = __builtin_fmaf(-2.0f, d2, tnz + s2);
        const float t3 = __builtin_fmaf(-2.0f, d3, tnz + s3);
        u64 p;
        p = ((u64)__float_as_uint(t0) << 32) | (u64)(kb0 + k + 0); if (p < best) best = p;
        p = ((u64)__float_as_uint(t1) << 32) | (u64)(kb0 + k + 1); if (p < best) best = p;
        p = ((u64)__float_as_uint(t2) << 32) | (u64)(kb0 + k + 2); if (p < best) best = p;
        p = ((u64)__float_as_uint(t3) << 32) | (u64)(kb0 + k + 3); if (p < best) best = p;
    }
    part[(size_t)slice * N_TOK + token] = best;
}

// ---------------------------------------------------------------------------
// Kernel C: combine 16 slice-partials (u64 min keeps first-index tie-break),
// write idx as float, histogram, gather z_q, write z_q_st = z + (z_q - z)
// exactly as the reference computes it, and accumulate sum((z_q - z)^2).
// (unchanged)
// ---------------------------------------------------------------------------
__global__ __launch_bounds__(256) void reduce_gather_kernel(
    const float* __restrict__ z, const float* __restrict__ cb,
    const u64* __restrict__ part, int* __restrict__ hist,
    float* __restrict__ lossAcc, float* __restrict__ out) {
    const int t = blockIdx.x * 256 + threadIdx.x;
    u64 best = part[t];
#pragma unroll
    for (int s = 1; s < NSLICE; ++s) {
        u64 p = part[(size_t)s * N_TOK + t];
        if (p < best) best = p;
    }
    const int idx = (int)(best & 0xFFFFFFFFull);
    out[IDX_OFF + t] = (float)idx;
    atomicAdd(&hist[idx], 1);

    const float4* ev = (const float4*)(cb + (size_t)idx * EDIM);
    const float4* zv = (const float4*)(z + (size_t)t * EDIM);
    float* o = out + ZQ_OFF + (size_t)t * EDIM;  // out+1: only 4B-aligned -> scalar stores
    float acc = 0.0f;
#pragma unroll
    for (int j = 0; j < 16; ++j) {
        float4 e = ev[j], zz = zv[j];
        float d;
        d = e.x - zz.x; o[4 * j + 0] = zz.x + d; acc = __builtin_fmaf(d, d, acc);
        d = e.y - zz.y; o[4 * j + 1] = zz.y + d; acc = __builtin_fmaf(d, d, acc);
        d = e.z - zz.z; o[4 * j + 2] = zz.z + d; acc = __builtin_fmaf(d, d, acc);
        d = e.w - zz.w; o[4 * j + 3] = zz.w + d; acc = __builtin_fmaf(d, d, acc);
    }
    __shared__ float red[256];
    red[threadIdx.x] = acc;
    __syncthreads();
    for (int s = 128; s > 0; s >>= 1) {
        if (threadIdx.x < s) red[threadIdx.x] += red[threadIdx.x + s];
        __syncthreads();
    }
    if (threadIdx.x == 0) atomicAdd(lossAcc, red[0]);
}

// ---------------------------------------------------------------------------
// Kernel D: perplexity from histogram + loss finalize. (unchanged)
// ---------------------------------------------------------------------------
__global__ __launch_bounds__(256) void finalize_kernel(
    const int* __restrict__ hist, const float* __restrict__ lossAcc,
    float* __restrict__ out) {
    __shared__ float red[256];
    float acc = 0.0f;
    for (int i = threadIdx.x; i < NE; i += 256) {
        float e = (float)hist[i] * (1.0f / 16384.0f);  // exact /n_tokens
        acc += e * logf(e + 1e-10f);
    }
    red[threadIdx.x] = acc;
    __syncthreads();
    for (int s = 128; s > 0; s >>= 1) {
        if (threadIdx.x < s) red[threadIdx.x] += red[threadIdx.x + s];
        __syncthreads();
    }
    if (threadIdx.x == 0) {
        out[PERP_OFF] = expf(-red[0]);
        float m = lossAcc[0] * (1.0f / 1048576.0f);    // exact /B*T*E
        out[0] = m + 0.25f * m;
    }
}

extern "C" void kernel_launch(void* const* d_in, const int* in_sizes, int n_in,
                              void* d_out, int out_size, void* d_ws, size_t ws_size,
                              hipStream_t stream) {
    const float* z  = (const float*)d_in[0];
    const float* cb = (const float*)d_in[1];
    float* out = (float*)d_out;

    char* ws = (char*)d_ws;
    u64*   part    = (u64*)ws;                                  // 2 MB
    float* nz      = (float*)(ws + (size_t)NSLICE * N_TOK * 8); // 64 KB
    float* ne      = nz + N_TOK;                                // 16 KB
    int*   hist    = (int*)(ne + NE);                           // 16 KB
    float* lossAcc = (float*)(hist + NE);                       // 4 B

    hipLaunchKernelGGL(norms_zero_kernel, dim3(80), dim3(256), 0, stream,
                       z, cb, nz, ne, hist, lossAcc);
    hipLaunchKernelGGL(dist_argmin_kernel,
                       dim3(N_TOK / 256, NSLICE), dim3(TPB), 0, stream,
                       z, cb, nz, ne, part);
    hipLaunchKernelGGL(reduce_gather_kernel, dim3(64), dim3(256), 0, stream,
                       z, cb, part, hist, lossAcc, out);
    hipLaunchKernelGGL(finalize_kernel, dim3(1), dim3(256), 0, stream,
                       hist, lossAcc, out);
}

// Round 8
// 258.983 us; speedup vs baseline: 2.9682x; 2.9682x over previous
//
#include <hip/hip_runtime.h>
#include <math.h>

#define N_TOK   16384
#define EDIM    64
#define NE      4096
#define NSLICE  16                       /* 16 slices x 256 codes */
#define TPB     256
#define ZQ_OFF  1
#define IDX_OFF (1 + N_TOK * EDIM)       /* 1048577 */
#define PERP_OFF (IDX_OFF + N_TOK)       /* 1064961 */

typedef unsigned long long u64;

// ---------------------------------------------------------------------------
// Kernel A: per-row squared norms replicating numpy pairwise_sum (n=64 path:
// 8 accumulators stride 8, then ((r0+r1)+(r2+r3))+((r4+r5)+(r6+r7))),
// with products ROUNDED before summation (contract off). Also zero-inits
// the histogram and loss accumulator in ws. (unchanged)
// ---------------------------------------------------------------------------
__global__ __launch_bounds__(256) void norms_zero_kernel(
    const float* __restrict__ z, const float* __restrict__ cb,
    float* __restrict__ nz, float* __restrict__ ne,
    int* __restrict__ hist, float* __restrict__ lossAcc) {
#pragma clang fp contract(off)
    int i = blockIdx.x * 256 + threadIdx.x;
    if (i < NE) hist[i] = 0;
    if (i == 0) lossAcc[0] = 0.0f;
    const float* row;
    float* dst;
    if (i < N_TOK)            { row = z  + (size_t)i * EDIM;           dst = nz + i; }
    else if (i < N_TOK + NE)  { row = cb + (size_t)(i - N_TOK) * EDIM; dst = ne + (i - N_TOK); }
    else return;

    float r[8];
#pragma unroll
    for (int j = 0; j < 8; ++j) { float v = row[j]; r[j] = v * v; }
#pragma unroll
    for (int b = 8; b < 64; b += 8) {
#pragma unroll
        for (int j = 0; j < 8; ++j) { float v = row[b + j]; r[j] = r[j] + v * v; }
    }
    dst[0] = ((r[0] + r[1]) + (r[2] + r[3])) + ((r[4] + r[5]) + (r[6] + r[7]));
}

// ---------------------------------------------------------------------------
// Kernel B (v9): r6's 16x8 tile with DIM-PHASED LDS (48 KB) for 3 blocks/CU.
// Design-space data: r=16 @2blk -> 135us (r1); r=21.3 @1blk -> 184us (r6,
// 80KB LDS seats only 1 block: occ 11.4%, latency-exposed); r=21.3 spilled
// -> 194us (r4/5); r=32 @1blk+shuffle -> 246us (r3); uniform global
// streaming -> 703us (r7, L2-latency-bound). Missing cell: r>=21 at
// >=2-3 blocks/CU. Fix r6's one defect: phase BOTH tiles over dims.
// Per (chunk, p): stage z 256tok x 32dims (32KB) + codes 128 x 32dims
// (16KB) = 48KB live -> 3 blocks/CU by LDS; r6's measured 164 VGPR ->
// 3 waves/SIMD by regs -> 12 waves/CU. acc[16][8] accumulates across the
// two phases (p=0: q=0..7, p=1: q=8..15) -> per-(token,code) chain is the
// SAME sequential q-ascending, x->w-ascending fp32 FMA chain as every
// passing round (bits identical -> ties exact). z restaged 4x/block from
// L2 (z is L2/L3-resident, ~+4us aggregate - noise).
// d = fma(-2, dot, tz+sne[k]); running strict-< argmin over ascending k
// == first index; u64 pack (d_bits<<32)|k then cross-cg LDS u64 min
// (d>0 so float bits monotone). Verified absmax=0 rounds 4-6.
// ---------------------------------------------------------------------------
__global__ __launch_bounds__(256, 1)
void dist_argmin_kernel(
    const float* __restrict__ z, const float* __restrict__ cb,
    const float* __restrict__ nz, const float* __restrict__ ne,
    u64* __restrict__ part) {
    __shared__ float4 zt[8 * 256];       // 32 KB: [ql][tok ^ q], one dim-phase
    __shared__ float4 ct[8 * 128];       // 16 KB: [ql][code ^ ql], one dim-phase
    const int tid   = threadIdx.x;
    const int tg    = tid & 15;          // token lane-group (16 tokens, stride 16)
    const int cg    = tid >> 4;          // code group (8 codes)
    const int tok0  = blockIdx.x * 256;
    const int kb0   = blockIdx.y * 256;  // slice base (256 codes = 2 chunks)

    const float4* zp = (const float4*)z + (size_t)tok0 * 16;
    const float4* cp = (const float4*)cb;

    float bd[16];
    int   bk[16];
#pragma unroll
    for (int i = 0; i < 16; ++i) { bd[i] = __builtin_inff(); bk[i] = 0; }

#pragma unroll 1
    for (int ch = 0; ch < 2; ++ch) {
        const int kb = kb0 + ch * 128;
        float acc[16][8];
#pragma unroll
        for (int i = 0; i < 16; ++i)
#pragma unroll
            for (int j = 0; j < 8; ++j) acc[i][j] = 0.0f;

#pragma unroll 1
        for (int p = 0; p < 2; ++p) {
            __syncthreads();             // previous phase's readers done
            // ---- stage z phase: 2048 float4, 8/thread; 8-lane groups read
            //      128B contiguous (full lines). Swizzle [ql][row ^ q].
#pragma unroll
            for (int r = 0; r < 8; ++r) {
                const int f   = r * 256 + tid;   // 0..2047
                const int row = f >> 3;          // local token
                const int ql  = f & 7;           // phase-local dim-group
                zt[ql * 256 + (row ^ (8 * p + ql))] = zp[row * 16 + 8 * p + ql];
            }
            // ---- stage code phase: 1024 float4, 4/thread.
#pragma unroll
            for (int r = 0; r < 4; ++r) {
                const int f    = r * 256 + tid;  // 0..1023
                const int code = f >> 3;         // local code
                const int ql   = f & 7;
                ct[ql * 128 + (code ^ ql)] =
                    cp[(size_t)(kb + code) * 16 + 8 * p + ql];
            }
            __syncthreads();

#pragma unroll 2
            for (int ql = 0; ql < 8; ++ql) {
                const int q = 8 * p + ql;        // global dim-group (ascending)
                float4 cf[8];
#pragma unroll
                for (int j = 0; j < 8; ++j)
                    cf[j] = ct[ql * 128 + ((cg * 8 + j) ^ ql)];
#pragma unroll
                for (int i = 0; i < 16; ++i) {
                    const float4 zf = zt[ql * 256 + ((i * 16 + tg) ^ q)];
#pragma unroll
                    for (int j = 0; j < 8; ++j) {
                        acc[i][j] = __builtin_fmaf(zf.x, cf[j].x, acc[i][j]);
                        acc[i][j] = __builtin_fmaf(zf.y, cf[j].y, acc[i][j]);
                        acc[i][j] = __builtin_fmaf(zf.z, cf[j].z, acc[i][j]);
                        acc[i][j] = __builtin_fmaf(zf.w, cf[j].w, acc[i][j]);
                    }
                }
            }
        }

        // ---- per-chunk epilogue: d + running argmin (strict <, k ascending)
        float sne[8];
#pragma unroll
        for (int j = 0; j < 8; ++j) sne[j] = ne[kb + cg * 8 + j];
#pragma unroll
        for (int i = 0; i < 16; ++i) {
            const float tz = nz[tok0 + i * 16 + tg];
#pragma unroll
            for (int j = 0; j < 8; ++j) {
                const float d = __builtin_fmaf(-2.0f, acc[i][j], tz + sne[j]);
                const int   k = kb + cg * 8 + j;
                if (d < bd[i]) { bd[i] = d; bk[i] = k; }
            }
        }
    }

    // ---- cross-thread (cg) reduction: overlay on zt (exactly 32 KB)
    __syncthreads();
    u64* red = (u64*)zt;                 // 16 cg x 256 tokens = 32 KB
#pragma unroll
    for (int i = 0; i < 16; ++i)
        red[cg * 256 + i * 16 + tg] =
            ((u64)__float_as_uint(bd[i]) << 32) | (u64)bk[i];
    __syncthreads();
    u64 b = red[tid];
#pragma unroll
    for (int s = 1; s < 16; ++s) {
        const u64 p = red[s * 256 + tid];
        if (p < b) b = p;
    }
    part[(size_t)blockIdx.y * N_TOK + tok0 + tid] = b;
}

// ---------------------------------------------------------------------------
// Kernel C: combine 16 slice-partials (u64 min keeps first-index tie-break),
// write idx as float, histogram, gather z_q, write z_q_st = z + (z_q - z)
// exactly as the reference computes it, and accumulate sum((z_q - z)^2).
// (unchanged)
// ---------------------------------------------------------------------------
__global__ __launch_bounds__(256) void reduce_gather_kernel(
    const float* __restrict__ z, const float* __restrict__ cb,
    const u64* __restrict__ part, int* __restrict__ hist,
    float* __restrict__ lossAcc, float* __restrict__ out) {
    const int t = blockIdx.x * 256 + threadIdx.x;
    u64 best = part[t];
#pragma unroll
    for (int s = 1; s < NSLICE; ++s) {
        u64 p = part[(size_t)s * N_TOK + t];
        if (p < best) best = p;
    }
    const int idx = (int)(best & 0xFFFFFFFFull);
    out[IDX_OFF + t] = (float)idx;
    atomicAdd(&hist[idx], 1);

    const float4* ev = (const float4*)(cb + (size_t)idx * EDIM);
    const float4* zv = (const float4*)(z + (size_t)t * EDIM);
    float* o = out + ZQ_OFF + (size_t)t * EDIM;  // out+1: only 4B-aligned -> scalar stores
    float acc = 0.0f;
#pragma unroll
    for (int j = 0; j < 16; ++j) {
        float4 e = ev[j], zz = zv[j];
        float d;
        d = e.x - zz.x; o[4 * j + 0] = zz.x + d; acc = __builtin_fmaf(d, d, acc);
        d = e.y - zz.y; o[4 * j + 1] = zz.y + d; acc = __builtin_fmaf(d, d, acc);
        d = e.z - zz.z; o[4 * j + 2] = zz.z + d; acc = __builtin_fmaf(d, d, acc);
        d = e.w - zz.w; o[4 * j + 3] = zz.w + d; acc = __builtin_fmaf(d, d, acc);
    }
    __shared__ float red[256];
    red[threadIdx.x] = acc;
    __syncthreads();
    for (int s = 128; s > 0; s >>= 1) {
        if (threadIdx.x < s) red[threadIdx.x] += red[threadIdx.x + s];
        __syncthreads();
    }
    if (threadIdx.x == 0) atomicAdd(lossAcc, red[0]);
}

// ---------------------------------------------------------------------------
// Kernel D: perplexity from histogram + loss finalize. (unchanged)
// ---------------------------------------------------------------------------
__global__ __launch_bounds__(256) void finalize_kernel(
    const int* __restrict__ hist, const float* __restrict__ lossAcc,
    float* __restrict__ out) {
    __shared__ float red[256];
    float acc = 0.0f;
    for (int i = threadIdx.x; i < NE; i += 256) {
        float e = (float)hist[i] * (1.0f / 16384.0f);  // exact /n_tokens
        acc += e * logf(e + 1e-10f);
    }
    red[threadIdx.x] = acc;
    __syncthreads();
    for (int s = 128; s > 0; s >>= 1) {
        if (threadIdx.x < s) red[threadIdx.x] += red[threadIdx.x + s];
        __syncthreads();
    }
    if (threadIdx.x == 0) {
        out[PERP_OFF] = expf(-red[0]);
        float m = lossAcc[0] * (1.0f / 1048576.0f);    // exact /B*T*E
        out[0] = m + 0.25f * m;
    }
}

extern "C" void kernel_launch(void* const* d_in, const int* in_sizes, int n_in,
                              void* d_out, int out_size, void* d_ws, size_t ws_size,
                              hipStream_t stream) {
    const float* z  = (const float*)d_in[0];
    const float* cb = (const float*)d_in[1];
    float* out = (float*)d_out;

    char* ws = (char*)d_ws;
    u64*   part    = (u64*)ws;                                  // 2 MB
    float* nz      = (float*)(ws + (size_t)NSLICE * N_TOK * 8); // 64 KB
    float* ne      = nz + N_TOK;                                // 16 KB
    int*   hist    = (int*)(ne + NE);                           // 16 KB
    float* lossAcc = (float*)(hist + NE);                       // 4 B

    hipLaunchKernelGGL(norms_zero_kernel, dim3(80), dim3(256), 0, stream,
                       z, cb, nz, ne, hist, lossAcc);
    hipLaunchKernelGGL(dist_argmin_kernel,
                       dim3(N_TOK / 256, NSLICE), dim3(TPB), 0, stream,
                       z, cb, nz, ne, part);
    hipLaunchKernelGGL(reduce_gather_kernel, dim3(64), dim3(256), 0, stream,
                       z, cb, part, hist, lossAcc, out);
    hipLaunchKernelGGL(finalize_kernel, dim3(1), dim3(256), 0, stream,
                       hist, lossAcc, out);
}